// Round 4
// baseline (511.828 us; speedup 1.0000x reference)
//
#include <hip/hip_runtime.h>

typedef unsigned short ushort;

typedef __bf16 bf16x8 __attribute__((ext_vector_type(8)));
typedef float  f32x4  __attribute__((ext_vector_type(4)));
typedef unsigned short u16x8 __attribute__((ext_vector_type(8)));

static constexpr int BB   = 32;
static constexpr int NN   = 577;   // N = NP+1
static constexpr int LL   = 576;   // NP
static constexpr int DIMC = 512;
static constexpr int BN   = BB * NN;  // 18464

// ---------------- workspace arena (bytes), total 98,828,288 (~94.3 MB) -----
// y1 (fp32 EMA fwd output) lives in d_out (37.8 MB, dead until k_out).
static constexpr size_t SZ_WQKVT = 1536ull * 512 * 2;        // 1,572,864
static constexpr size_t SZ_WOUTT = 512ull * 512 * 2;         //   524,288
static constexpr size_t SZ_QK    = (size_t)BN * 1024 * 2;    // 37,814,272
static constexpr size_t SZ_V     = (size_t)BN * 512 * 2;     // 18,907,136
static constexpr size_t SZ_VT    = 256ull * 64 * 640 * 2;    // 20,971,520
static constexpr size_t OFF_WQKVT = 0;
static constexpr size_t OFF_WOUTT = OFF_WQKVT + SZ_WQKVT;
static constexpr size_t OFF_QTAB  = OFF_WOUTT + SZ_WOUTT;
static constexpr size_t OFF_CTAB  = OFF_QTAB + 65536;
static constexpr size_t OFF_QK    = OFF_CTAB + 65536;
static constexpr size_t OFF_V     = OFF_QK + SZ_QK;
static constexpr size_t OFF_REGION= OFF_V + SZ_V;            // 58,949,632
static constexpr size_t OFF_XM    = OFF_REGION;              // xm dead after k_qkv
static constexpr size_t OFF_VT    = OFF_REGION;              // vt overlays xm
static constexpr size_t OFF_AO    = OFF_REGION + SZ_VT;
static constexpr size_t WS_NEEDED = OFF_AO + SZ_V;           // 98,828,288

// ---------------- helpers ----------------
__device__ __forceinline__ ushort bf16bits(float f) {
  unsigned int u = __builtin_bit_cast(unsigned int, f);
  u = (u + 0x7fffu + ((u >> 16) & 1u)) >> 16;
  return (ushort)u;
}
__device__ __forceinline__ float sigmoidf_(float z) { return 1.f / (1.f + __expf(-z)); }
__device__ __forceinline__ float siluf(float z)     { return z / (1.f + __expf(-z)); }
__device__ __forceinline__ float redmax16(float v) {
  v = fmaxf(v, __shfl_xor(v, 1)); v = fmaxf(v, __shfl_xor(v, 2));
  v = fmaxf(v, __shfl_xor(v, 4)); v = fmaxf(v, __shfl_xor(v, 8));
  return v;
}
__device__ __forceinline__ float redsum16(float v) {
  v += __shfl_xor(v, 1); v += __shfl_xor(v, 2);
  v += __shfl_xor(v, 4); v += __shfl_xor(v, 8);
  return v;
}

// ---------------- prep: EMA tables + bf16 transposed weights ----------------
__global__ __launch_bounds__(256) void k_prep(
    const float* __restrict__ delta, const float* __restrict__ alpha,
    const float* __restrict__ beta,  const float* __restrict__ gamma,
    const float* __restrict__ Wqk,   const float* __restrict__ Wv,
    const float* __restrict__ Wout,
    float* __restrict__ qtab, float* __restrict__ ctab,
    ushort* __restrict__ Wqkvt, ushort* __restrict__ Woutt)
{
  int idx = blockIdx.x * 256 + threadIdx.x;
  if (idx < 16384) {
    float p = sigmoidf_(delta[idx]);
    float q = 1.f - p * sigmoidf_(alpha[idx]);
    qtab[idx] = q;
    ctab[idx] = p * beta[idx] * gamma[idx] * 0.25f;   // scale = sqrt(1/16)
  }
  int i2 = idx - 16384;                                // Wqkv_t: [1536][512]
  if (i2 >= 0 && i2 < 1536 * 512) {
    int n = i2 >> 9, k = i2 & 511;
    float w = (n < 1024) ? Wqk[k * 1024 + n] : Wv[k * 512 + (n - 1024)];
    Wqkvt[i2] = bf16bits(w);
  }
  int i3 = i2 - 1536 * 512;                            // Wout_t: [512][512]
  if (i3 >= 0 && i3 < 512 * 512) {
    int n = i3 >> 9, k = i3 & 511;
    Woutt[i3] = bf16bits(Wout[k * 512 + n]);
  }
}

// ---------------- EMA forward scan (causal): y1[i] = sum_{u<=i} c q^{i-u} x[u]
__global__ __launch_bounds__(64) void k_ema_fwd(
    const float* __restrict__ x, const float* __restrict__ qtab,
    const float* __restrict__ ctab, float* __restrict__ y1)
{
  const int d = blockIdx.x * 64 + threadIdx.x;
  const int b = blockIdx.y;
  float q[16], c[16], h[16];
  #pragma unroll
  for (int n = 0; n < 16; ++n) { q[n] = qtab[d*16+n]; c[n] = ctab[d*16+n]; h[n] = 0.f; }
  const float* xp = x  + ((size_t)b * NN + 1) * DIMC + d;   // x[:,1:]
  float*       yp = y1 + ((size_t)b * LL)     * DIMC + d;
  float xn[8];
  #pragma unroll
  for (int u = 0; u < 8; ++u) xn[u] = xp[u * DIMC];
  for (int blk = 0; blk < 72; ++blk) {
    float xv[8];
    #pragma unroll
    for (int u = 0; u < 8; ++u) xv[u] = xn[u];
    if (blk < 71) {
      #pragma unroll
      for (int u = 0; u < 8; ++u) xn[u] = xp[((blk + 1) * 8 + u) * DIMC];
    }
    #pragma unroll
    for (int u = 0; u < 8; ++u) {
      float xx = xv[u], y = 0.f;
      #pragma unroll
      for (int n = 0; n < 16; ++n) { h[n] = fmaf(q[n], h[n], xx); y = fmaf(c[n], h[n], y); }
      yp[(blk * 8 + u) * DIMC] = y;
    }
  }
}

// ------------- EMA backward scan + combine + silu + cls -> xm (bf16) -------
// y2[i] = sum_{u>=i} c q^{u-i} x[u]  (includes u=i); g[i] = x[i] + q*g[i+1]
__global__ __launch_bounds__(64) void k_ema_bwd(
    const float* __restrict__ x, const float* __restrict__ qtab,
    const float* __restrict__ ctab, const float* __restrict__ y1,
    const float* __restrict__ omega, ushort* __restrict__ xm)
{
  const int d = blockIdx.x * 64 + threadIdx.x;
  const int b = blockIdx.y;
  float q[16], c[16], g[16];
  #pragma unroll
  for (int n = 0; n < 16; ++n) { q[n] = qtab[(d+512)*16+n]; c[n] = ctab[(d+512)*16+n]; g[n] = 0.f; }
  const float om = omega[d];
  const float* xp  = x  + ((size_t)b * NN + 1) * DIMC + d;
  const float* yp  = y1 + ((size_t)b * LL)     * DIMC + d;
  ushort*      xmp = xm + ((size_t)b * NN + 1) * DIMC + d;
  #pragma unroll 8
  for (int t = 0; t < 576; ++t) {
    int i = 575 - t;
    float xv = xp[i * DIMC];
    #pragma unroll
    for (int n = 0; n < 16; ++n) g[n] = fmaf(q[n], g[n], xv);
    float y2 = 0.f;
    #pragma unroll
    for (int n = 0; n < 16; ++n) y2 = fmaf(c[n], g[n], y2);
    xmp[i * DIMC] = bf16bits(siluf(yp[i * DIMC] + y2 + xv * om));
  }
  // cls row passes through unchanged
  xm[((size_t)b * NN) * DIMC + d] = bf16bits(x[((size_t)b * NN) * DIMC + d]);
}

// ---------------- QKV GEMM: xm[18464,512] @ Wqkv_t[1536,512]^T -------------
__global__ __launch_bounds__(256) void k_qkv(
    const ushort* __restrict__ A, const ushort* __restrict__ Bt,
    ushort* __restrict__ qk, ushort* __restrict__ v)
{
  __shared__ alignas(16) ushort lA[128 * 32];
  __shared__ alignas(16) ushort lB[128 * 32];
  const int tid = threadIdx.x, wv = tid >> 6, lane = tid & 63;
  const int quad = lane >> 4, c16 = lane & 15;
  const int row0 = blockIdx.y * 128, n0 = blockIdx.x * 128;
  const int wm = (wv >> 1) * 64, wn = (wv & 1) * 64;
  f32x4 z4 = {0.f, 0.f, 0.f, 0.f};
  f32x4 acc[4][4];
  #pragma unroll
  for (int mi = 0; mi < 4; ++mi)
    #pragma unroll
    for (int ni = 0; ni < 4; ++ni) acc[mi][ni] = z4;

  for (int kt = 0; kt < 16; ++kt) {
    const int k0 = kt * 32;
    // stage A,B tiles (plain vector loads; LDS layout identical to GLD16 ver.)
    u16x8 sa[2], sb[2];
    #pragma unroll
    for (int it = 0; it < 2; ++it) {
      int ch = it * 256 + tid;           // [0,512)
      int r = ch >> 2, cc = ch & 3;
      int grow = row0 + r; if (grow > BN - 1) grow = BN - 1;
      sa[it] = *(const u16x8*)(A + (size_t)grow * 512 + k0 + cc * 8);
      sb[it] = *(const u16x8*)(Bt + (size_t)(n0 + r) * 512 + k0 + cc * 8);
    }
    __syncthreads();   // previous iteration's LDS reads done
    #pragma unroll
    for (int it = 0; it < 2; ++it) {
      int ch = it * 256 + tid;
      int r = ch >> 2, cc = ch & 3;
      *(u16x8*)(lA + r * 32 + cc * 8) = sa[it];
      *(u16x8*)(lB + r * 32 + cc * 8) = sb[it];
    }
    __syncthreads();   // staging visible
    bf16x8 af[4], bfv[4];
    #pragma unroll
    for (int mi = 0; mi < 4; ++mi)
      af[mi] = *(const bf16x8*)(lA + (wm + mi * 16 + c16) * 32 + quad * 8);
    #pragma unroll
    for (int ni = 0; ni < 4; ++ni)
      bfv[ni] = *(const bf16x8*)(lB + (wn + ni * 16 + c16) * 32 + quad * 8);
    #pragma unroll
    for (int mi = 0; mi < 4; ++mi)
      #pragma unroll
      for (int ni = 0; ni < 4; ++ni)
        acc[mi][ni] = __builtin_amdgcn_mfma_f32_16x16x32_bf16(af[mi], bfv[ni], acc[mi][ni], 0, 0, 0);
  }
  const bool isv = (n0 >= 1024);
  #pragma unroll
  for (int mi = 0; mi < 4; ++mi) {
    #pragma unroll
    for (int r = 0; r < 4; ++r) {
      int grow = row0 + wm + mi * 16 + quad * 4 + r;
      if (grow < BN) {
        #pragma unroll
        for (int ni = 0; ni < 4; ++ni) {
          int col = n0 + wn + ni * 16 + c16;
          ushort vb = bf16bits(acc[mi][ni][r]);
          if (!isv) qk[(size_t)grow * 1024 + col] = vb;
          else      v[(size_t)grow * 512 + (col - 1024)] = vb;
        }
      }
    }
  }
}

// ---------------- transpose v -> vt[bh*64+dh][640] (zero-padded j>=577) ----
__global__ __launch_bounds__(256) void k_vtrans(
    const ushort* __restrict__ v, ushort* __restrict__ vt)
{
  __shared__ alignas(16) ushort lt[64 * 72];
  const int tid = threadIdx.x;
  const int bh = blockIdx.y, b = bh >> 3, h = bh & 7;
  const int j0 = blockIdx.x * 64;
  #pragma unroll
  for (int pass = 0; pass < 2; ++pass) {
    int cch = pass * 256 + tid;
    int jl = cch >> 3, cc = cch & 7;
    int gj = j0 + jl;
    u16x8 val = {0, 0, 0, 0, 0, 0, 0, 0};
    if (gj < 577) val = *(const u16x8*)(v + ((size_t)(b * NN + gj)) * 512 + h * 64 + cc * 8);
    *(u16x8*)(lt + jl * 72 + cc * 8) = val;
  }
  __syncthreads();
  #pragma unroll
  for (int pass = 0; pass < 2; ++pass) {
    int cch = pass * 256 + tid;
    int dh = cch >> 3, jc = cch & 7;
    u16x8 o;
    #pragma unroll
    for (int e = 0; e < 8; ++e) o[e] = lt[(jc * 8 + e) * 72 + dh];
    *(u16x8*)(vt + ((size_t)(bh * 64 + dh)) * 640 + j0 + jc * 8) = o;
  }
}

// -------- fused flash attention: O = softmax(QK^T/8) V + Bias V ------------
// Dual accumulators: accp (online-softmax, rescaled) + accb (bias, exact).
__global__ __launch_bounds__(256) void k_fattn(
    const ushort* __restrict__ qk, const ushort* __restrict__ vt,
    const float* __restrict__ relb, ushort* __restrict__ ao)
{
  __shared__ alignas(16) ushort lq[128 * 64];
  __shared__ alignas(16) ushort lk[64 * 64];
  __shared__ alignas(16) ushort lv[64 * 64];
  __shared__ alignas(16) ushort lp[128 * 64];
  __shared__ float lbias[1153];
  const int tid = threadIdx.x, wv = tid >> 6, lane = tid & 63;
  const int quad = lane >> 4, c16 = lane & 15;
  const int bh = blockIdx.y, b = bh >> 3, h = bh & 7;
  const int i0 = blockIdx.x * 128, wm = wv * 32;
  for (int t = tid; t < 1153; t += 256) lbias[t] = relb[t];
  // stage Q tile (128 x 64): 1024 chunks of 8 ushorts
  #pragma unroll
  for (int it = 0; it < 4; ++it) {
    int ch = it * 256 + tid;
    int r = ch >> 3, cc = ch & 7;
    int gi = i0 + r; if (gi > 576) gi = 576;
    *(u16x8*)(lq + r * 64 + cc * 8) =
        *(const u16x8*)(qk + ((size_t)(b * NN + gi)) * 1024 + h * 64 + cc * 8);
  }
  float mrun[2][4], lrun[2][4];
  #pragma unroll
  for (int ms = 0; ms < 2; ++ms)
    #pragma unroll
    for (int r = 0; r < 4; ++r) { mrun[ms][r] = -3.0e38f; lrun[ms][r] = 0.f; }
  f32x4 z4 = {0.f, 0.f, 0.f, 0.f};
  f32x4 accp[2][4], accb[2][4];
  #pragma unroll
  for (int ms = 0; ms < 2; ++ms)
    #pragma unroll
    for (int ns = 0; ns < 4; ++ns) { accp[ms][ns] = z4; accb[ms][ns] = z4; }

  for (int jt = 0; jt < 10; ++jt) {
    const int j0 = jt * 64;
    // stage K and V^T tiles (64 x 64 each): 512 chunks each
    u16x8 sk[2], sv[2];
    #pragma unroll
    for (int it = 0; it < 2; ++it) {
      int ch = it * 256 + tid;
      int r = ch >> 3, cc = ch & 7;
      int gj = j0 + r; if (gj > 576) gj = 576;
      sk[it] = *(const u16x8*)(qk + ((size_t)(b * NN + gj)) * 1024 + 512 + h * 64 + cc * 8);
      sv[it] = *(const u16x8*)(vt + ((size_t)(bh * 64 + r)) * 640 + j0 + cc * 8);
    }
    __syncthreads();                       // previous iter's lk/lv reads done
    #pragma unroll
    for (int it = 0; it < 2; ++it) {
      int ch = it * 256 + tid;
      int r = ch >> 3, cc = ch & 7;
      *(u16x8*)(lk + r * 64 + cc * 8) = sk[it];
      *(u16x8*)(lv + r * 64 + cc * 8) = sv[it];
    }
    __syncthreads();                       // staging visible
    // ---- S = Q K^T
    f32x4 dacc[2][4];
    #pragma unroll
    for (int ms = 0; ms < 2; ++ms)
      #pragma unroll
      for (int ns = 0; ns < 4; ++ns) dacc[ms][ns] = z4;
    #pragma unroll
    for (int kk = 0; kk < 2; ++kk) {
      bf16x8 aq[2], bk[4];
      #pragma unroll
      for (int ms = 0; ms < 2; ++ms)
        aq[ms] = *(const bf16x8*)(lq + (wm + ms * 16 + c16) * 64 + kk * 32 + quad * 8);
      #pragma unroll
      for (int ns = 0; ns < 4; ++ns)
        bk[ns] = *(const bf16x8*)(lk + (ns * 16 + c16) * 64 + kk * 32 + quad * 8);
      #pragma unroll
      for (int ms = 0; ms < 2; ++ms)
        #pragma unroll
        for (int ns = 0; ns < 4; ++ns)
          dacc[ms][ns] = __builtin_amdgcn_mfma_f32_16x16x32_bf16(aq[ms], bk[ns], dacc[ms][ns], 0, 0, 0);
    }
    // ---- online softmax update; write P~ (bf16) to lp (wave-private rows)
    #pragma unroll
    for (int ms = 0; ms < 2; ++ms) {
      float dv[4][4];
      #pragma unroll
      for (int ns = 0; ns < 4; ++ns) {
        const bool ok = (j0 + ns * 16 + c16) < 577;
        #pragma unroll
        for (int r = 0; r < 4; ++r) dv[ns][r] = ok ? dacc[ms][ns][r] * 0.125f : -3.0e38f;
      }
      #pragma unroll
      for (int r = 0; r < 4; ++r) {
        float tm = fmaxf(fmaxf(dv[0][r], dv[1][r]), fmaxf(dv[2][r], dv[3][r]));
        tm = redmax16(tm);
        float nm = fmaxf(mrun[ms][r], tm);
        float e0 = __expf(dv[0][r] - nm), e1 = __expf(dv[1][r] - nm);
        float e2 = __expf(dv[2][r] - nm), e3 = __expf(dv[3][r] - nm);
        float s = redsum16(e0 + e1 + e2 + e3);
        float alpha = __expf(mrun[ms][r] - nm);
        lrun[ms][r] = lrun[ms][r] * alpha + s;
        mrun[ms][r] = nm;
        #pragma unroll
        for (int ns = 0; ns < 4; ++ns) accp[ms][ns][r] *= alpha;
        const int lrow = wm + ms * 16 + quad * 4 + r;
        lp[lrow * 64 +  0 + c16] = bf16bits(e0);
        lp[lrow * 64 + 16 + c16] = bf16bits(e1);
        lp[lrow * 64 + 32 + c16] = bf16bits(e2);
        lp[lrow * 64 + 48 + c16] = bf16bits(e3);
      }
    }
    __syncthreads();                       // lp writes -> lp reads
    // ---- O += P~ V  and  O_b += Bias V
    #pragma unroll
    for (int kk = 0; kk < 2; ++kk) {
      bf16x8 ap[2], ab[2], bV[4];
      #pragma unroll
      for (int ms = 0; ms < 2; ++ms)
        ap[ms] = *(const bf16x8*)(lp + (wm + ms * 16 + c16) * 64 + kk * 32 + quad * 8);
      #pragma unroll
      for (int ms = 0; ms < 2; ++ms) {
        u16x8 abu;
        const int base = 576 + j0 + kk * 32 + quad * 8 - (i0 + wm + ms * 16 + c16);
        #pragma unroll
        for (int e = 0; e < 8; ++e) {
          int bi = base + e;
          bi = bi < 0 ? 0 : (bi > 1152 ? 1152 : bi);
          abu[e] = bf16bits(lbias[bi]);
        }
        ab[ms] = __builtin_bit_cast(bf16x8, abu);
      }
      #pragma unroll
      for (int ns = 0; ns < 4; ++ns)
        bV[ns] = *(const bf16x8*)(lv + (ns * 16 + c16) * 64 + kk * 32 + quad * 8);
      #pragma unroll
      for (int ms = 0; ms < 2; ++ms)
        #pragma unroll
        for (int ns = 0; ns < 4; ++ns) {
          accp[ms][ns] = __builtin_amdgcn_mfma_f32_16x16x32_bf16(ap[ms], bV[ns], accp[ms][ns], 0, 0, 0);
          accb[ms][ns] = __builtin_amdgcn_mfma_f32_16x16x32_bf16(ab[ms], bV[ns], accb[ms][ns], 0, 0, 0);
        }
    }
  }
  // ---- epilogue: O = accp/l + accb -> ao (bf16)
  #pragma unroll
  for (int ms = 0; ms < 2; ++ms)
    #pragma unroll
    for (int r = 0; r < 4; ++r) {
      int ii = i0 + wm + ms * 16 + quad * 4 + r;
      if (ii < 577) {
        float li = 1.f / lrun[ms][r];
        #pragma unroll
        for (int ns = 0; ns < 4; ++ns)
          ao[((size_t)(b * NN + ii)) * 512 + h * 64 + ns * 16 + c16] =
              bf16bits(accp[ms][ns][r] * li + accb[ms][ns][r]);
      }
    }
}

// ---------------- out GEMM: ao[18464,512] @ Wout_t[512,512]^T + b_out -----
__global__ __launch_bounds__(256) void k_out(
    const ushort* __restrict__ A, const ushort* __restrict__ Bt,
    const float* __restrict__ bout, float* __restrict__ out)
{
  __shared__ alignas(16) ushort lA[128 * 32];
  __shared__ alignas(16) ushort lB[128 * 32];
  const int tid = threadIdx.x, wv = tid >> 6, lane = tid & 63;
  const int quad = lane >> 4, c16 = lane & 15;
  const int row0 = blockIdx.y * 128, n0 = blockIdx.x * 128;
  const int wm = (wv >> 1) * 64, wn = (wv & 1) * 64;
  f32x4 z4 = {0.f, 0.f, 0.f, 0.f};
  f32x4 acc[4][4];
  #pragma unroll
  for (int mi = 0; mi < 4; ++mi)
    #pragma unroll
    for (int ni = 0; ni < 4; ++ni) acc[mi][ni] = z4;

  for (int kt = 0; kt < 16; ++kt) {
    const int k0 = kt * 32;
    u16x8 sa[2], sb[2];
    #pragma unroll
    for (int it = 0; it < 2; ++it) {
      int ch = it * 256 + tid;
      int r = ch >> 2, cc = ch & 3;
      int grow = row0 + r; if (grow > BN - 1) grow = BN - 1;
      sa[it] = *(const u16x8*)(A + (size_t)grow * 512 + k0 + cc * 8);
      sb[it] = *(const u16x8*)(Bt + (size_t)(n0 + r) * 512 + k0 + cc * 8);
    }
    __syncthreads();
    #pragma unroll
    for (int it = 0; it < 2; ++it) {
      int ch = it * 256 + tid;
      int r = ch >> 2, cc = ch & 3;
      *(u16x8*)(lA + r * 32 + cc * 8) = sa[it];
      *(u16x8*)(lB + r * 32 + cc * 8) = sb[it];
    }
    __syncthreads();
    bf16x8 af[4], bfv[4];
    #pragma unroll
    for (int mi = 0; mi < 4; ++mi)
      af[mi] = *(const bf16x8*)(lA + (wm + mi * 16 + c16) * 32 + quad * 8);
    #pragma unroll
    for (int ni = 0; ni < 4; ++ni)
      bfv[ni] = *(const bf16x8*)(lB + (wn + ni * 16 + c16) * 32 + quad * 8);
    #pragma unroll
    for (int mi = 0; mi < 4; ++mi)
      #pragma unroll
      for (int ni = 0; ni < 4; ++ni)
        acc[mi][ni] = __builtin_amdgcn_mfma_f32_16x16x32_bf16(af[mi], bfv[ni], acc[mi][ni], 0, 0, 0);
  }
  #pragma unroll
  for (int mi = 0; mi < 4; ++mi) {
    #pragma unroll
    for (int r = 0; r < 4; ++r) {
      int grow = row0 + wm + mi * 16 + quad * 4 + r;
      if (grow < BN) {
        #pragma unroll
        for (int ni = 0; ni < 4; ++ni) {
          int col = n0 + wn + ni * 16 + c16;
          out[(size_t)grow * 512 + col] = acc[mi][ni][r] + bout[col];
        }
      }
    }
  }
}

// ---------------- launch ----------------
extern "C" void kernel_launch(void* const* d_in, const int* in_sizes, int n_in,
                              void* d_out, int out_size, void* d_ws, size_t ws_size,
                              hipStream_t stream) {
  (void)in_sizes; (void)n_in; (void)out_size;
  if (ws_size < WS_NEEDED) return;   // diagnostic guard: fail clean, not crash
  const float* x    = (const float*)d_in[0];
  const float* Wqk  = (const float*)d_in[1];
  const float* Wv   = (const float*)d_in[2];
  const float* Wout = (const float*)d_in[3];
  const float* bout = (const float*)d_in[4];
  const float* relb = (const float*)d_in[5];
  const float* edel = (const float*)d_in[6];
  const float* ealp = (const float*)d_in[7];
  const float* ebet = (const float*)d_in[8];
  const float* egam = (const float*)d_in[9];
  const float* eome = (const float*)d_in[10];

  char* ws = (char*)d_ws;
  ushort* Wqkvt = (ushort*)(ws + OFF_WQKVT);
  ushort* Woutt = (ushort*)(ws + OFF_WOUTT);
  float*  qtab  = (float*)(ws + OFF_QTAB);
  float*  ctab  = (float*)(ws + OFF_CTAB);
  ushort* qkb   = (ushort*)(ws + OFF_QK);
  ushort* vb    = (ushort*)(ws + OFF_V);
  ushort* xm    = (ushort*)(ws + OFF_XM);
  ushort* vtb   = (ushort*)(ws + OFF_VT);
  ushort* aob   = (ushort*)(ws + OFF_AO);
  float*  outp  = (float*)d_out;
  float*  y1    = outp;              // d_out doubles as fp32 scratch (dead until k_out)

  k_prep<<<dim3(4160), dim3(256), 0, stream>>>(edel, ealp, ebet, egam, Wqk, Wv, Wout,
                                               qtab, ctab, Wqkvt, Woutt);
  k_ema_fwd<<<dim3(8, 32), dim3(64), 0, stream>>>(x, qtab, ctab, y1);
  k_ema_bwd<<<dim3(8, 32), dim3(64), 0, stream>>>(x, qtab, ctab, y1, eome, xm);
  k_qkv<<<dim3(12, 145), dim3(256), 0, stream>>>(xm, Wqkvt, qkb, vb);
  k_vtrans<<<dim3(10, 256), dim3(256), 0, stream>>>(vb, vtb);
  k_fattn<<<dim3(5, 256), dim3(256), 0, stream>>>(qkb, vtb, relb, aob);
  k_out<<<dim3(4, 145), dim3(256), 0, stream>>>(aob, Woutt, bout, outp);
}

// Round 5
// 364.771 us; speedup vs baseline: 1.4032x; 1.4032x over previous
//
#include <hip/hip_runtime.h>

typedef unsigned short ushort;

typedef __bf16 bf16x8 __attribute__((ext_vector_type(8)));
typedef float  f32x4  __attribute__((ext_vector_type(4)));
typedef unsigned short u16x8 __attribute__((ext_vector_type(8)));
typedef unsigned short u16x4 __attribute__((ext_vector_type(4)));

static constexpr int BB   = 32;
static constexpr int NN   = 577;   // N = NP+1
static constexpr int LL   = 576;   // NP
static constexpr int DIMC = 512;
static constexpr int BN   = BB * NN;  // 18464

// ---------------- workspace arena (bytes), total 98,828,288 (~94.3 MB) -----
// y1 (fp32 EMA fwd) lives in d_out; y2 (fp32 EMA bwd) lives in the QK region
// (dead until k_qkv writes it, after k_ema_comb consumed y2).
static constexpr size_t SZ_WQKVT = 1536ull * 512 * 2;
static constexpr size_t SZ_WOUTT = 512ull * 512 * 2;
static constexpr size_t SZ_QK    = (size_t)BN * 1024 * 2;    // 37,814,272
static constexpr size_t SZ_V     = (size_t)BN * 512 * 2;     // 18,907,136
static constexpr size_t SZ_VT    = 256ull * 64 * 640 * 2;    // 20,971,520
static constexpr size_t OFF_WQKVT = 0;
static constexpr size_t OFF_WOUTT = OFF_WQKVT + SZ_WQKVT;
static constexpr size_t OFF_QTAB  = OFF_WOUTT + SZ_WOUTT;
static constexpr size_t OFF_CTAB  = OFF_QTAB + 65536;
static constexpr size_t OFF_QK    = OFF_CTAB + 65536;
static constexpr size_t OFF_V     = OFF_QK + SZ_QK;
static constexpr size_t OFF_REGION= OFF_V + SZ_V;
static constexpr size_t OFF_XM    = OFF_REGION;              // xm dead after k_qkv
static constexpr size_t OFF_VT    = OFF_REGION;              // vt overlays xm
static constexpr size_t OFF_AO    = OFF_REGION + SZ_VT;
static constexpr size_t WS_NEEDED = OFF_AO + SZ_V;           // 98,828,288

// ---------------- helpers ----------------
__device__ __forceinline__ ushort bf16bits(float f) {
  unsigned int u = __builtin_bit_cast(unsigned int, f);
  u = (u + 0x7fffu + ((u >> 16) & 1u)) >> 16;
  return (ushort)u;
}
__device__ __forceinline__ float sigmoidf_(float z) { return 1.f / (1.f + __expf(-z)); }
__device__ __forceinline__ float siluf(float z)     { return z / (1.f + __expf(-z)); }
__device__ __forceinline__ float redsum16(float v) {
  v += __shfl_xor(v, 1); v += __shfl_xor(v, 2);
  v += __shfl_xor(v, 4); v += __shfl_xor(v, 8);
  return v;
}

// ---------------- prep: EMA tables + bf16 transposed weights ----------------
__global__ __launch_bounds__(256) void k_prep(
    const float* __restrict__ delta, const float* __restrict__ alpha,
    const float* __restrict__ beta,  const float* __restrict__ gamma,
    const float* __restrict__ Wqk,   const float* __restrict__ Wv,
    const float* __restrict__ Wout,
    float* __restrict__ qtab, float* __restrict__ ctab,
    ushort* __restrict__ Wqkvt, ushort* __restrict__ Woutt)
{
  int idx = blockIdx.x * 256 + threadIdx.x;
  if (idx < 16384) {
    float p = sigmoidf_(delta[idx]);
    float q = 1.f - p * sigmoidf_(alpha[idx]);
    qtab[idx] = q;
    ctab[idx] = p * beta[idx] * gamma[idx] * 0.25f;   // scale = sqrt(1/16)
  }
  int i2 = idx - 16384;                                // Wqkv_t: [1536][512]
  if (i2 >= 0 && i2 < 1536 * 512) {
    int n = i2 >> 9, k = i2 & 511;
    float w = (n < 1024) ? Wqk[k * 1024 + n] : Wv[k * 512 + (n - 1024)];
    Wqkvt[i2] = bf16bits(w);
  }
  int i3 = i2 - 1536 * 512;                            // Wout_t: [512][512]
  if (i3 >= 0 && i3 < 512 * 512) {
    int n = i3 >> 9, k = i3 & 511;
    Woutt[i3] = bf16bits(Wout[k * 512 + n]);
  }
}

// -------- EMA dual scan: fwd (blocks 0-7) -> y1, bwd (blocks 8-15) -> y2 ----
// Independent directions run concurrently: 512 waves instead of 2x256 serial.
__global__ __launch_bounds__(64) void k_ema_scan(
    const float* __restrict__ x, const float* __restrict__ qtab,
    const float* __restrict__ ctab, float* __restrict__ y1, float* __restrict__ y2)
{
  const int bx = blockIdx.x;
  const int b  = blockIdx.y;
  if (bx < 8) {
    const int d = bx * 64 + threadIdx.x;
    float q[16], c[16], h[16];
    #pragma unroll
    for (int n = 0; n < 16; ++n) { q[n] = qtab[d*16+n]; c[n] = ctab[d*16+n]; h[n] = 0.f; }
    const float* xp = x  + ((size_t)b * NN + 1) * DIMC + d;
    float*       yp = y1 + ((size_t)b * LL)     * DIMC + d;
    float xn[8];
    #pragma unroll
    for (int u = 0; u < 8; ++u) xn[u] = xp[u * DIMC];
    for (int blk = 0; blk < 72; ++blk) {
      float xv[8];
      #pragma unroll
      for (int u = 0; u < 8; ++u) xv[u] = xn[u];
      if (blk < 71) {
        #pragma unroll
        for (int u = 0; u < 8; ++u) xn[u] = xp[((blk + 1) * 8 + u) * DIMC];
      }
      #pragma unroll
      for (int u = 0; u < 8; ++u) {
        float xx = xv[u], y = 0.f;
        #pragma unroll
        for (int n = 0; n < 16; ++n) { h[n] = fmaf(q[n], h[n], xx); y = fmaf(c[n], h[n], y); }
        yp[(blk * 8 + u) * DIMC] = y;
      }
    }
  } else {
    const int d = (bx - 8) * 64 + threadIdx.x;
    float q[16], c[16], g[16];
    #pragma unroll
    for (int n = 0; n < 16; ++n) { q[n] = qtab[(d+512)*16+n]; c[n] = ctab[(d+512)*16+n]; g[n] = 0.f; }
    const float* xp = x  + ((size_t)b * NN + 1) * DIMC + d;
    float*       yp = y2 + ((size_t)b * LL)     * DIMC + d;
    float xn[8];
    #pragma unroll
    for (int u = 0; u < 8; ++u) xn[u] = xp[(568 + u) * DIMC];
    for (int blk = 71; blk >= 0; --blk) {
      float xv[8];
      #pragma unroll
      for (int u = 0; u < 8; ++u) xv[u] = xn[u];
      if (blk > 0) {
        #pragma unroll
        for (int u = 0; u < 8; ++u) xn[u] = xp[((blk - 1) * 8 + u) * DIMC];
      }
      #pragma unroll
      for (int u = 7; u >= 0; --u) {
        float xx = xv[u], y = 0.f;
        #pragma unroll
        for (int n = 0; n < 16; ++n) { g[n] = fmaf(q[n], g[n], xx); y = fmaf(c[n], g[n], y); }
        yp[(blk * 8 + u) * DIMC] = y;
      }
    }
  }
}

// -------- combine: xm = bf16(silu(y1+y2+x*omega)); cls row passthrough ------
__global__ __launch_bounds__(256) void k_ema_comb(
    const float* __restrict__ x, const float* __restrict__ y1,
    const float* __restrict__ y2, const float* __restrict__ omega,
    ushort* __restrict__ xm)
{
  size_t v = (size_t)blockIdx.x * 256 + threadIdx.x;   // vec4 index
  size_t e = v * 4;
  int n = (int)(e >> 9);
  int d = (int)(e & 511);
  int b = n / 577;
  int i = n - b * 577;
  f32x4 xv = *(const f32x4*)(x + e);
  u16x4 o;
  if (i == 0) {
    #pragma unroll
    for (int k = 0; k < 4; ++k) o[k] = bf16bits(xv[k]);
  } else {
    size_t ey = ((size_t)b * LL + (i - 1)) * DIMC + d;
    f32x4 a  = *(const f32x4*)(y1 + ey);
    f32x4 c2 = *(const f32x4*)(y2 + ey);
    f32x4 om = *(const f32x4*)(omega + d);
    #pragma unroll
    for (int k = 0; k < 4; ++k) o[k] = bf16bits(siluf(a[k] + c2[k] + xv[k] * om[k]));
  }
  *(u16x4*)(xm + e) = o;
}

// ---------------- QKV GEMM: xm[18464,512] @ Wqkv_t[1536,512]^T -------------
// q columns (n0<512) pre-scaled by 0.125 for attention. Rows padded 32->40
// ushorts (80 B) to stagger LDS banks (2-way, free).
__global__ __launch_bounds__(256) void k_qkv(
    const ushort* __restrict__ A, const ushort* __restrict__ Bt,
    ushort* __restrict__ qk, ushort* __restrict__ v)
{
  __shared__ alignas(16) ushort lA[128 * 40];
  __shared__ alignas(16) ushort lB[128 * 40];
  const int tid = threadIdx.x, wv = tid >> 6, lane = tid & 63;
  const int quad = lane >> 4, c16 = lane & 15;
  const int row0 = blockIdx.y * 128, n0 = blockIdx.x * 128;
  const int wm = (wv >> 1) * 64, wn = (wv & 1) * 64;
  f32x4 z4 = {0.f, 0.f, 0.f, 0.f};
  f32x4 acc[4][4];
  #pragma unroll
  for (int mi = 0; mi < 4; ++mi)
    #pragma unroll
    for (int ni = 0; ni < 4; ++ni) acc[mi][ni] = z4;

  for (int kt = 0; kt < 16; ++kt) {
    const int k0 = kt * 32;
    u16x8 sa[2], sb[2];
    #pragma unroll
    for (int it = 0; it < 2; ++it) {
      int ch = it * 256 + tid;
      int r = ch >> 2, cc = ch & 3;
      int grow = row0 + r; if (grow > BN - 1) grow = BN - 1;
      sa[it] = *(const u16x8*)(A + (size_t)grow * 512 + k0 + cc * 8);
      sb[it] = *(const u16x8*)(Bt + (size_t)(n0 + r) * 512 + k0 + cc * 8);
    }
    __syncthreads();
    #pragma unroll
    for (int it = 0; it < 2; ++it) {
      int ch = it * 256 + tid;
      int r = ch >> 2, cc = ch & 3;
      *(u16x8*)(lA + r * 40 + cc * 8) = sa[it];
      *(u16x8*)(lB + r * 40 + cc * 8) = sb[it];
    }
    __syncthreads();
    bf16x8 af[4], bfv[4];
    #pragma unroll
    for (int mi = 0; mi < 4; ++mi)
      af[mi] = *(const bf16x8*)(lA + (wm + mi * 16 + c16) * 40 + quad * 8);
    #pragma unroll
    for (int ni = 0; ni < 4; ++ni)
      bfv[ni] = *(const bf16x8*)(lB + (wn + ni * 16 + c16) * 40 + quad * 8);
    #pragma unroll
    for (int mi = 0; mi < 4; ++mi)
      #pragma unroll
      for (int ni = 0; ni < 4; ++ni)
        acc[mi][ni] = __builtin_amdgcn_mfma_f32_16x16x32_bf16(af[mi], bfv[ni], acc[mi][ni], 0, 0, 0);
  }
  const bool isv = (n0 >= 1024);
  const float osc = (n0 < 512) ? 0.125f : 1.0f;      // fold 1/sqrt(DH) into q
  #pragma unroll
  for (int mi = 0; mi < 4; ++mi) {
    #pragma unroll
    for (int r = 0; r < 4; ++r) {
      int grow = row0 + wm + mi * 16 + quad * 4 + r;
      if (grow < BN) {
        #pragma unroll
        for (int ni = 0; ni < 4; ++ni) {
          int col = n0 + wn + ni * 16 + c16;
          ushort vb = bf16bits(acc[mi][ni][r] * osc);
          if (!isv) qk[(size_t)grow * 1024 + col] = vb;
          else      v[(size_t)grow * 512 + (col - 1024)] = vb;
        }
      }
    }
  }
}

// ---------------- transpose v -> vt[bh*64+dh][640] (zero-padded j>=577) ----
__global__ __launch_bounds__(256) void k_vtrans(
    const ushort* __restrict__ v, ushort* __restrict__ vt)
{
  __shared__ alignas(16) ushort lt[64 * 72];
  const int tid = threadIdx.x;
  const int bh = blockIdx.y, b = bh >> 3, h = bh & 7;
  const int j0 = blockIdx.x * 64;
  #pragma unroll
  for (int pass = 0; pass < 2; ++pass) {
    int cch = pass * 256 + tid;
    int jl = cch >> 3, cc = cch & 7;
    int gj = j0 + jl;
    u16x8 val = {0, 0, 0, 0, 0, 0, 0, 0};
    if (gj < 577) val = *(const u16x8*)(v + ((size_t)(b * NN + gj)) * 512 + h * 64 + cc * 8);
    *(u16x8*)(lt + jl * 72 + cc * 8) = val;
  }
  __syncthreads();
  #pragma unroll
  for (int pass = 0; pass < 2; ++pass) {
    int cch = pass * 256 + tid;
    int dh = cch >> 3, jc = cch & 7;
    u16x8 o;
    #pragma unroll
    for (int e = 0; e < 8; ++e) o[e] = lt[(jc * 8 + e) * 72 + dh];
    *(u16x8*)(vt + ((size_t)(bh * 64 + dh)) * 640 + j0 + jc * 8) = o;
  }
}

// -------- fused flash attention: O = softmax(QK^T) V + Bias V --------------
// Static softmax (scores bounded ~|50| << 88 -> raw exp safe in fp32): no
// running max, no rescale; per-lane partial row-sums, one redsum16 at end.
// All LDS tiles XOR-chunk-swizzled (chunk ^= row&7) to kill 16-way conflicts.
__global__ __launch_bounds__(256) void k_fattn(
    const ushort* __restrict__ qk, const ushort* __restrict__ vt,
    const float* __restrict__ relb, ushort* __restrict__ ao)
{
  __shared__ alignas(16) ushort lq[128 * 64];
  __shared__ alignas(16) ushort lk[64 * 64];
  __shared__ alignas(16) ushort lv[64 * 64];
  __shared__ alignas(16) ushort lp[128 * 64];
  __shared__ ushort lbias16[1280];     // bf16 bias at +64 offset, pad-safe
  const int tid = threadIdx.x, wv = tid >> 6, lane = tid & 63;
  const int quad = lane >> 4, c16 = lane & 15;
  const int hc16 = c16 >> 3, lo16 = c16 & 7;
  const int bh = blockIdx.y, b = bh >> 3, h = bh & 7;
  const int i0 = blockIdx.x * 128, wm = wv * 32;
  for (int t = tid; t < 1280; t += 256) {
    int idx = t - 64;
    lbias16[t] = (idx >= 0 && idx < 1153) ? bf16bits(relb[idx]) : (ushort)0;
  }
  // stage Q tile (128 x 64), swizzled
  #pragma unroll
  for (int it = 0; it < 4; ++it) {
    int ch = it * 256 + tid;
    int r = ch >> 3, cc = ch & 7;
    int gi = i0 + r; if (gi > 576) gi = 576;
    *(u16x8*)(lq + r * 64 + ((cc ^ (r & 7)) * 8)) =
        *(const u16x8*)(qk + ((size_t)(b * NN + gi)) * 1024 + h * 64 + cc * 8);
  }
  float lsum[2][4];
  #pragma unroll
  for (int ms = 0; ms < 2; ++ms)
    #pragma unroll
    for (int r = 0; r < 4; ++r) lsum[ms][r] = 0.f;
  f32x4 z4 = {0.f, 0.f, 0.f, 0.f};
  f32x4 accp[2][4], accb[2][4];
  #pragma unroll
  for (int ms = 0; ms < 2; ++ms)
    #pragma unroll
    for (int ns = 0; ns < 4; ++ns) { accp[ms][ns] = z4; accb[ms][ns] = z4; }

  for (int jt = 0; jt < 10; ++jt) {
    const int j0 = jt * 64;
    u16x8 sk[2], sv[2];
    #pragma unroll
    for (int it = 0; it < 2; ++it) {
      int ch = it * 256 + tid;
      int r = ch >> 3, cc = ch & 7;
      int gj = j0 + r; if (gj > 576) gj = 576;
      sk[it] = *(const u16x8*)(qk + ((size_t)(b * NN + gj)) * 1024 + 512 + h * 64 + cc * 8);
      sv[it] = *(const u16x8*)(vt + ((size_t)(bh * 64 + r)) * 640 + j0 + cc * 8);
    }
    __syncthreads();                       // prior lk/lv/lp readers done
    #pragma unroll
    for (int it = 0; it < 2; ++it) {
      int ch = it * 256 + tid;
      int r = ch >> 3, cc = ch & 7;
      int pc = (cc ^ (r & 7)) * 8;
      *(u16x8*)(lk + r * 64 + pc) = sk[it];
      *(u16x8*)(lv + r * 64 + pc) = sv[it];
    }
    __syncthreads();                       // staging visible
    // ---- S = Q K^T (Q pre-scaled by 1/8)
    f32x4 dacc[2][4];
    #pragma unroll
    for (int ms = 0; ms < 2; ++ms)
      #pragma unroll
      for (int ns = 0; ns < 4; ++ns) dacc[ms][ns] = z4;
    #pragma unroll
    for (int kk = 0; kk < 2; ++kk) {
      bf16x8 aq[2], bk[4];
      const int ck = kk * 4 + quad;
      #pragma unroll
      for (int ms = 0; ms < 2; ++ms) {
        const int row = wm + ms * 16 + c16;
        aq[ms] = *(const bf16x8*)(lq + row * 64 + ((ck ^ (row & 7)) * 8));
      }
      #pragma unroll
      for (int ns = 0; ns < 4; ++ns) {
        const int row = ns * 16 + c16;
        bk[ns] = *(const bf16x8*)(lk + row * 64 + ((ck ^ (row & 7)) * 8));
      }
      #pragma unroll
      for (int ms = 0; ms < 2; ++ms)
        #pragma unroll
        for (int ns = 0; ns < 4; ++ns)
          dacc[ms][ns] = __builtin_amdgcn_mfma_f32_16x16x32_bf16(aq[ms], bk[ns], dacc[ms][ns], 0, 0, 0);
    }
    // ---- static softmax: e = exp(s); write bf16 e to lp; per-lane partials
    #pragma unroll
    for (int ms = 0; ms < 2; ++ms) {
      #pragma unroll
      for (int r = 0; r < 4; ++r) {
        float ex[4];
        #pragma unroll
        for (int ns = 0; ns < 4; ++ns) {
          float e = __expf(dacc[ms][ns][r]);
          if (jt == 9 && (j0 + ns * 16 + c16) >= 577) e = 0.f;
          ex[ns] = e;
        }
        lsum[ms][r] += (ex[0] + ex[1]) + (ex[2] + ex[3]);
        const int lrow = wm + ms * 16 + quad * 4 + r;
        const int xr = lrow & 7;
        #pragma unroll
        for (int ns = 0; ns < 4; ++ns)
          lp[lrow * 64 + (((ns * 2 + hc16) ^ xr) * 8) + lo16] = bf16bits(ex[ns]);
      }
    }
    __syncthreads();                       // lp writes -> lp reads
    // ---- O += P~ V  and  O_b += Bias V
    #pragma unroll
    for (int kk = 0; kk < 2; ++kk) {
      bf16x8 ap[2], ab[2], bV[4];
      const int ck = kk * 4 + quad;
      #pragma unroll
      for (int ms = 0; ms < 2; ++ms) {
        const int row = wm + ms * 16 + c16;
        ap[ms] = *(const bf16x8*)(lp + row * 64 + ((ck ^ (row & 7)) * 8));
      }
      #pragma unroll
      for (int ms = 0; ms < 2; ++ms) {
        u16x8 abu;
        const int base = 64 + 576 + j0 + kk * 32 + quad * 8 - (i0 + wm + ms * 16 + c16);
        #pragma unroll
        for (int e = 0; e < 8; ++e) abu[e] = lbias16[base + e];
        ab[ms] = __builtin_bit_cast(bf16x8, abu);
      }
      #pragma unroll
      for (int ns = 0; ns < 4; ++ns) {
        const int row = ns * 16 + c16;
        bV[ns] = *(const bf16x8*)(lv + row * 64 + ((ck ^ (row & 7)) * 8));
      }
      #pragma unroll
      for (int ms = 0; ms < 2; ++ms)
        #pragma unroll
        for (int ns = 0; ns < 4; ++ns) {
          accp[ms][ns] = __builtin_amdgcn_mfma_f32_16x16x32_bf16(ap[ms], bV[ns], accp[ms][ns], 0, 0, 0);
          accb[ms][ns] = __builtin_amdgcn_mfma_f32_16x16x32_bf16(ab[ms], bV[ns], accb[ms][ns], 0, 0, 0);
        }
    }
  }
  // ---- epilogue: O = accp/l + accb
  float li[2][4];
  #pragma unroll
  for (int ms = 0; ms < 2; ++ms)
    #pragma unroll
    for (int r = 0; r < 4; ++r) li[ms][r] = 1.f / redsum16(lsum[ms][r]);
  #pragma unroll
  for (int ms = 0; ms < 2; ++ms)
    #pragma unroll
    for (int r = 0; r < 4; ++r) {
      int ii = i0 + wm + ms * 16 + quad * 4 + r;
      if (ii < 577) {
        #pragma unroll
        for (int ns = 0; ns < 4; ++ns)
          ao[((size_t)(b * NN + ii)) * 512 + h * 64 + ns * 16 + c16] =
              bf16bits(accp[ms][ns][r] * li[ms][r] + accb[ms][ns][r]);
      }
    }
}

// ---------------- out GEMM: ao[18464,512] @ Wout_t[512,512]^T + b_out -----
__global__ __launch_bounds__(256) void k_out(
    const ushort* __restrict__ A, const ushort* __restrict__ Bt,
    const float* __restrict__ bout, float* __restrict__ out)
{
  __shared__ alignas(16) ushort lA[128 * 40];
  __shared__ alignas(16) ushort lB[128 * 40];
  const int tid = threadIdx.x, wv = tid >> 6, lane = tid & 63;
  const int quad = lane >> 4, c16 = lane & 15;
  const int row0 = blockIdx.y * 128, n0 = blockIdx.x * 128;
  const int wm = (wv >> 1) * 64, wn = (wv & 1) * 64;
  f32x4 z4 = {0.f, 0.f, 0.f, 0.f};
  f32x4 acc[4][4];
  #pragma unroll
  for (int mi = 0; mi < 4; ++mi)
    #pragma unroll
    for (int ni = 0; ni < 4; ++ni) acc[mi][ni] = z4;

  for (int kt = 0; kt < 16; ++kt) {
    const int k0 = kt * 32;
    u16x8 sa[2], sb[2];
    #pragma unroll
    for (int it = 0; it < 2; ++it) {
      int ch = it * 256 + tid;
      int r = ch >> 2, cc = ch & 3;
      int grow = row0 + r; if (grow > BN - 1) grow = BN - 1;
      sa[it] = *(const u16x8*)(A + (size_t)grow * 512 + k0 + cc * 8);
      sb[it] = *(const u16x8*)(Bt + (size_t)(n0 + r) * 512 + k0 + cc * 8);
    }
    __syncthreads();
    #pragma unroll
    for (int it = 0; it < 2; ++it) {
      int ch = it * 256 + tid;
      int r = ch >> 2, cc = ch & 3;
      *(u16x8*)(lA + r * 40 + cc * 8) = sa[it];
      *(u16x8*)(lB + r * 40 + cc * 8) = sb[it];
    }
    __syncthreads();
    bf16x8 af[4], bfv[4];
    #pragma unroll
    for (int mi = 0; mi < 4; ++mi)
      af[mi] = *(const bf16x8*)(lA + (wm + mi * 16 + c16) * 40 + quad * 8);
    #pragma unroll
    for (int ni = 0; ni < 4; ++ni)
      bfv[ni] = *(const bf16x8*)(lB + (wn + ni * 16 + c16) * 40 + quad * 8);
    #pragma unroll
    for (int mi = 0; mi < 4; ++mi)
      #pragma unroll
      for (int ni = 0; ni < 4; ++ni)
        acc[mi][ni] = __builtin_amdgcn_mfma_f32_16x16x32_bf16(af[mi], bfv[ni], acc[mi][ni], 0, 0, 0);
  }
  #pragma unroll
  for (int mi = 0; mi < 4; ++mi) {
    #pragma unroll
    for (int r = 0; r < 4; ++r) {
      int grow = row0 + wm + mi * 16 + quad * 4 + r;
      if (grow < BN) {
        #pragma unroll
        for (int ni = 0; ni < 4; ++ni) {
          int col = n0 + wn + ni * 16 + c16;
          out[(size_t)grow * 512 + col] = acc[mi][ni][r] + bout[col];
        }
      }
    }
  }
}

// ---------------- launch ----------------
extern "C" void kernel_launch(void* const* d_in, const int* in_sizes, int n_in,
                              void* d_out, int out_size, void* d_ws, size_t ws_size,
                              hipStream_t stream) {
  (void)in_sizes; (void)n_in; (void)out_size;
  if (ws_size < WS_NEEDED) return;   // fail clean, not crash
  const float* x    = (const float*)d_in[0];
  const float* Wqk  = (const float*)d_in[1];
  const float* Wv   = (const float*)d_in[2];
  const float* Wout = (const float*)d_in[3];
  const float* bout = (const float*)d_in[4];
  const float* relb = (const float*)d_in[5];
  const float* edel = (const float*)d_in[6];
  const float* ealp = (const float*)d_in[7];
  const float* ebet = (const float*)d_in[8];
  const float* egam = (const float*)d_in[9];
  const float* eome = (const float*)d_in[10];

  char* ws = (char*)d_ws;
  ushort* Wqkvt = (ushort*)(ws + OFF_WQKVT);
  ushort* Woutt = (ushort*)(ws + OFF_WOUTT);
  float*  qtab  = (float*)(ws + OFF_QTAB);
  float*  ctab  = (float*)(ws + OFF_CTAB);
  ushort* qkb   = (ushort*)(ws + OFF_QK);
  ushort* vb    = (ushort*)(ws + OFF_V);
  ushort* xm    = (ushort*)(ws + OFF_XM);
  ushort* vtb   = (ushort*)(ws + OFF_VT);
  ushort* aob   = (ushort*)(ws + OFF_AO);
  float*  outp  = (float*)d_out;
  float*  y1    = outp;                        // d_out as fp32 scratch
  float*  y2    = (float*)(ws + OFF_QK);       // QK region dead until k_qkv

  k_prep<<<dim3(4160), dim3(256), 0, stream>>>(edel, ealp, ebet, egam, Wqk, Wv, Wout,
                                               qtab, ctab, Wqkvt, Woutt);
  k_ema_scan<<<dim3(16, 32), dim3(64), 0, stream>>>(x, qtab, ctab, y1, y2);
  k_ema_comb<<<dim3(9232), dim3(256), 0, stream>>>(x, y1, y2, eome, xm);
  k_qkv<<<dim3(12, 145), dim3(256), 0, stream>>>(xm, Wqkvt, qkb, vb);
  k_vtrans<<<dim3(10, 256), dim3(256), 0, stream>>>(vb, vtb);
  k_fattn<<<dim3(5, 256), dim3(256), 0, stream>>>(qkb, vtb, relb, aob);
  k_out<<<dim3(4, 145), dim3(256), 0, stream>>>(aob, Woutt, bout, outp);
}